// Round 10
// baseline (157.634 us; speedup 1.0000x reference)
//
#include <hip/hip_runtime.h>
#include <math.h>

// Problem constants (from reference): V=3, B=2, C=64, NS=32, H=128, W=128
constexpr int NV = 3;
constexpr int NB = 2;
constexpr int NC = 64;
constexpr int NSC = 32;
constexpr int NH = 128;
constexpr int NW = 128;
constexpr int NSB = 16;  // ns values per block-pass (ns-inner for epipolar locality)

typedef _Float16 h2_t __attribute__((ext_vector_type(2)));

// ---------------------------------------------------------------------------
// DPP helpers (VALU cross-lane, no DS pipe).
// ---------------------------------------------------------------------------
template <int CTRL>
__device__ __forceinline__ float dpp_add(float x) {
    int s = __builtin_amdgcn_update_dpp(0, __float_as_int(x), CTRL, 0xf, 0xf, true);
    return x + __int_as_float(s);
}

__device__ __forceinline__ float dot2acc(h2_t a, float acc) {
#if __has_builtin(__builtin_amdgcn_fdot2)
    return __builtin_amdgcn_fdot2(a, a, acc, false);
#else
    float x = (float)a.x, y = (float)a.y;
    return acc + x * x + y * y;
#endif
}

__device__ __forceinline__ h2_t pack2(float a, float b) {
#if __has_builtin(__builtin_amdgcn_cvt_pkrtz)
    return __builtin_bit_cast(h2_t, __builtin_amdgcn_cvt_pkrtz(a, b));
#else
    h2_t r = { (_Float16)a, (_Float16)b };
    return r;
#endif
}

__device__ __forceinline__ unsigned int gc(const uint4& v, int j) {
    return j == 0 ? v.x : j == 1 ? v.y : j == 2 ? v.z : v.w;
}

// ---------------------------------------------------------------------------
// 4x4 inverse (adjugate, double precision) — mirrors jnp.linalg.inv fidelity
// ---------------------------------------------------------------------------
__device__ void inv4x4(const double* m, double* out) {
    double inv[16];
    inv[0]  =  m[5]*m[10]*m[15] - m[5]*m[11]*m[14] - m[9]*m[6]*m[15] + m[9]*m[7]*m[14] + m[13]*m[6]*m[11] - m[13]*m[7]*m[10];
    inv[4]  = -m[4]*m[10]*m[15] + m[4]*m[11]*m[14] + m[8]*m[6]*m[15] - m[8]*m[7]*m[14] - m[12]*m[6]*m[11] + m[12]*m[7]*m[10];
    inv[8]  =  m[4]*m[9]*m[15]  - m[4]*m[11]*m[13] - m[8]*m[5]*m[15] + m[8]*m[7]*m[13] + m[12]*m[5]*m[11] - m[12]*m[7]*m[9];
    inv[12] = -m[4]*m[9]*m[14]  + m[4]*m[10]*m[13] + m[8]*m[5]*m[14] - m[8]*m[6]*m[13] - m[12]*m[5]*m[10] + m[12]*m[6]*m[9];
    inv[1]  = -m[1]*m[10]*m[15] + m[1]*m[11]*m[14] + m[9]*m[2]*m[15] - m[9]*m[3]*m[14] - m[13]*m[2]*m[11] + m[13]*m[3]*m[10];
    inv[5]  =  m[0]*m[10]*m[15] - m[0]*m[11]*m[14] - m[8]*m[2]*m[15] + m[8]*m[3]*m[14] + m[12]*m[2]*m[11] - m[12]*m[3]*m[10];
    inv[9]  = -m[0]*m[9]*m[15]  + m[0]*m[11]*m[13] + m[8]*m[1]*m[15] - m[8]*m[3]*m[13] - m[12]*m[1]*m[11] + m[12]*m[3]*m[9];
    inv[13] =  m[0]*m[9]*m[14]  - m[0]*m[10]*m[13] - m[8]*m[1]*m[14] + m[8]*m[2]*m[13] + m[12]*m[1]*m[10] - m[12]*m[2]*m[9];
    inv[2]  =  m[1]*m[6]*m[15]  - m[1]*m[7]*m[14]  - m[5]*m[2]*m[15] + m[5]*m[3]*m[14] + m[13]*m[2]*m[7]  - m[13]*m[3]*m[6];
    inv[6]  = -m[0]*m[6]*m[15]  + m[0]*m[7]*m[14]  + m[4]*m[2]*m[15] - m[4]*m[3]*m[14] - m[12]*m[2]*m[7]  + m[12]*m[3]*m[6];
    inv[10] =  m[0]*m[5]*m[15]  - m[0]*m[7]*m[13]  - m[4]*m[1]*m[15] + m[4]*m[3]*m[13] + m[12]*m[1]*m[7]  - m[12]*m[3]*m[5];
    inv[14] = -m[0]*m[5]*m[14]  + m[0]*m[6]*m[13]  + m[4]*m[1]*m[14] - m[4]*m[2]*m[13] - m[12]*m[1]*m[6]  + m[12]*m[2]*m[5];
    inv[3]  = -m[1]*m[6]*m[11]  + m[1]*m[7]*m[10]  + m[5]*m[2]*m[11] - m[5]*m[3]*m[10] - m[9]*m[2]*m[7]   + m[9]*m[3]*m[6];
    inv[7]  =  m[0]*m[6]*m[11]  - m[0]*m[7]*m[10]  - m[4]*m[2]*m[11] + m[4]*m[3]*m[10] + m[8]*m[2]*m[7]   - m[8]*m[3]*m[6];
    inv[11] = -m[0]*m[5]*m[11]  + m[0]*m[7]*m[9]   + m[4]*m[1]*m[11] - m[4]*m[3]*m[9]  - m[8]*m[1]*m[7]   + m[8]*m[3]*m[5];
    inv[15] =  m[0]*m[5]*m[10]  - m[0]*m[6]*m[9]   - m[4]*m[1]*m[10] + m[4]*m[2]*m[9]  + m[8]*m[1]*m[6]   - m[8]*m[2]*m[5];
    double det = m[0]*inv[0] + m[1]*inv[4] + m[2]*inv[8] + m[3]*inv[12];
    det = 1.0 / det;
    for (int i = 0; i < 16; ++i) out[i] = inv[i] * det;
}

__device__ void mat4mul(const double* a, const double* b, double* o) {
    for (int i = 0; i < 4; ++i)
        for (int j = 0; j < 4; ++j) {
            double s = 0.0;
            for (int k = 0; k < 4; ++k) s += a[i*4+k] * b[k*4+j];
            o[i*4+j] = s;
        }
}

// ---------------------------------------------------------------------------
// Transpose + f16 compress: (V*B, C, H, W) fp32 -> (V*B, H*W, C) f16.
// One block per (vb, y) row. Block (0,0) additionally computes the homography
// rot/trans (threads 0..3), zeroes cost (4..67) and the counter (68).
// ---------------------------------------------------------------------------
__global__ __launch_bounds__(256) void transpose_kernel(const float* __restrict__ in,
                                                        unsigned int* __restrict__ out,
                                                        const float* __restrict__ intr,
                                                        const float* __restrict__ c2w,
                                                        float* __restrict__ rt,
                                                        float* __restrict__ cost,
                                                        unsigned int* __restrict__ counter) {
    __shared__ float tile[NC][NW + 1];
    const int y  = blockIdx.x;
    const int vb = blockIdx.y;

    for (int i = threadIdx.x; i < NC * NW; i += 256) {
        int c = i >> 7;
        int x = i & (NW - 1);
        tile[c][x] = in[((size_t)(vb * NC + c) * NH + y) * NW + x];
    }
    __syncthreads();
    // dst: per pixel a record of 64 f16 = 32 uints
    unsigned int* dst = out + ((size_t)vb * NH + y) * NW * (NC / 2);
    for (int i = threadIdx.x; i < NW * (NC / 2); i += 256) {
        int x  = i >> 5;         // /32
        int cp = i & 31;         // channel pair
        h2_t h = { (_Float16)tile[2 * cp][x], (_Float16)tile[2 * cp + 1][x] };
        dst[x * (NC / 2) + cp] = __builtin_bit_cast(unsigned int, h);
    }

    // ---- fused setup (one block only) ----
    if (blockIdx.x == 0 && blockIdx.y == 0) {
        int t = threadIdx.x;
        if (t >= 4 && t < 4 + NB * NSC) cost[t - 4] = 0.f;
        if (t == 4 + NB * NSC) *counter = 0u;
        if (t < 2 * NB) {
            int vi = t >> 1;
            int b  = t & 1;
            int v  = vi + 1;

            double src_c2w[16], ref_c2w[16];
            for (int i = 0; i < 16; ++i) {
                src_c2w[i] = (double)c2w[(v * NB + b) * 16 + i];
                ref_c2w[i] = (double)c2w[(0 * NB + b) * 16 + i];
            }
            double src_w2c[16], ref_w2c[16];
            inv4x4(src_c2w, src_w2c);
            inv4x4(ref_c2w, ref_w2c);

            double srcP[16], refP[16];
            for (int i = 0; i < 16; ++i) { srcP[i] = src_w2c[i]; refP[i] = ref_w2c[i]; }
            for (int r = 0; r < 3; ++r)
                for (int c = 0; c < 3; ++c) {
                    srcP[r*4+c] = (double)intr[(v * NB + b) * 9 + r*3 + c];
                    refP[r*4+c] = (double)intr[(0 * NB + b) * 9 + r*3 + c];
                }

            double M1[16], M2[16], M2inv[16];
            mat4mul(srcP, src_w2c, M1);
            mat4mul(refP, ref_w2c, M2);
            inv4x4(M2, M2inv);
            double proj[16];
            mat4mul(M1, M2inv, proj);

            float* o = rt + (vi * NB + b) * 12;
            o[0] = (float)proj[0];  o[1] = (float)proj[1];  o[2]  = (float)proj[2];
            o[3] = (float)proj[4];  o[4] = (float)proj[5];  o[5]  = (float)proj[6];
            o[6] = (float)proj[8];  o[7] = (float)proj[9];  o[8]  = (float)proj[10];
            o[9] = (float)proj[3];  o[10] = (float)proj[7]; o[11] = (float)proj[11];
        }
    }
}

// ---------------------------------------------------------------------------
// Geometry record: tap base index (uint4 units), packed neighbor offsets,
// 4 bilinear weights (f16, pre-negated). 16 B -> one ds op.
// ---------------------------------------------------------------------------
struct alignas(16) GeomRec {
    int base;
    int xoyo;          // xo | (yo<<16), in uint4 units
    unsigned int w01;  // h2 {-w00, -w01}
    unsigned int w23;  // h2 {-w10, -w11}
};

struct G4 {            // expanded form
    int t0, t1, t2, t3;
    h2_t w0s, w1s, w2s, w3s;  // splatted negated weights
};

__device__ __forceinline__ G4 expand(GeomRec g) {
    G4 o;
    int xo = g.xoyo & 0xffff;
    int yo = g.xoyo >> 16;
    o.t0 = g.base;
    o.t1 = g.base + xo;
    o.t2 = g.base + yo;
    o.t3 = g.base + yo + xo;
    h2_t w01 = __builtin_bit_cast(h2_t, g.w01);
    h2_t w23 = __builtin_bit_cast(h2_t, g.w23);
    o.w0s = h2_t{w01.x, w01.x};
    o.w1s = h2_t{w01.y, w01.y};
    o.w2s = h2_t{w23.x, w23.x};
    o.w3s = h2_t{w23.y, w23.y};
    return o;
}

// Bilinear combine for both views + DPP reduce -> wave total (valid lane 63).
__device__ __forceinline__ float combine(const uint4& f0u, const G4& g0, const G4& g1,
                                         const uint4& a0, const uint4& a1,
                                         const uint4& a2, const uint4& a3,
                                         const uint4& b0, const uint4& b1,
                                         const uint4& b2, const uint4& b3) {
    float sq1 = 0.f, sq2 = 0.f;
    h2_t r[4];
#pragma unroll
    for (int j = 0; j < 4; ++j) {
        h2_t rr = __builtin_bit_cast(h2_t, gc(f0u, j));
        rr += __builtin_bit_cast(h2_t, gc(a0, j)) * g0.w0s;
        rr += __builtin_bit_cast(h2_t, gc(a1, j)) * g0.w1s;
        rr += __builtin_bit_cast(h2_t, gc(a2, j)) * g0.w2s;
        rr += __builtin_bit_cast(h2_t, gc(a3, j)) * g0.w3s;
        r[j] = rr;
        sq1 = dot2acc(rr, sq1);
    }
#pragma unroll
    for (int j = 0; j < 4; ++j) {
        h2_t rr = r[j];
        rr += __builtin_bit_cast(h2_t, gc(b0, j)) * g1.w0s;
        rr += __builtin_bit_cast(h2_t, gc(b1, j)) * g1.w1s;
        rr += __builtin_bit_cast(h2_t, gc(b2, j)) * g1.w2s;
        rr += __builtin_bit_cast(h2_t, gc(b3, j)) * g1.w3s;
        sq2 = dot2acc(rr, sq2);
    }
    // 8-lane group reduce (row_shr prefix; tails at lanes 7,15,...)
    sq1 = dpp_add<0x111>(sq1);
    sq1 = dpp_add<0x112>(sq1);
    sq1 = dpp_add<0x114>(sq1);
    sq2 = dpp_add<0x111>(sq2);
    sq2 = dpp_add<0x112>(sq2);
    sq2 = dpp_add<0x114>(sq2);
    float sv = sqrtf(sq1) + sqrtf(sq2);
    sv = dpp_add<0x118>(sv);   // row_shr:8
    sv = dpp_add<0x142>(sv);   // row_bcast:15
    sv = dpp_add<0x143>(sv);   // row_bcast:31 -> wave total in lane 63
    return sv;
}

// ---------------------------------------------------------------------------
// Main cost kernel v9.
// Phase 1: lane-parallel geometry -> GeomRec in LDS (as v8).
// Phase 2: branch-free double-buffered pipeline. Two NAMED tap-buffer sets
//          (A/B), rolled loop of NSB/2 double-steps:
//            issue B(i+1) -> combine A(i) -> issue A(i+2, clamped) -> combine B(i+1)
//          8 loads always outstanding during each combine (vmcnt(8) waits,
//          never a full drain). No register rotation, no conditional loads.
// Grid: (H*W/32, NS/NSB, B), block 256.
// ---------------------------------------------------------------------------
__global__ __launch_bounds__(256, 4) void cost_kernel(
    const unsigned int* __restrict__ ftb, // (V, B, H*W, C) f16 features
    const float* __restrict__ depth,      // (B, H, W)
    const float* __restrict__ scale,      // (B, NS)
    const float* __restrict__ rt,         // (2, B, 12)
    float* __restrict__ cost,             // (B, NS) -- zeroed by transpose
    unsigned int* __restrict__ counter,   // completion counter -- zeroed
    float* __restrict__ outp,             // (B,) final output
    int total_blocks)
{
    const int tid  = threadIdx.x;
    const int lane = tid & 63;
    const int wv   = tid >> 6;
    const int nsg  = blockIdx.y;
    const int b    = blockIdx.z;

    __shared__ float s_lds[NSB];
    __shared__ float d_lds[32];
    __shared__ GeomRec geom[2][NSB][32];
    __shared__ float red[4][NSB];

    if (tid < NSB) s_lds[tid] = scale[b * NSC + nsg * NSB + tid];
    if (tid < 32)  d_lds[tid] = depth[b * NH * NW + blockIdx.x * 32 + tid];
    __syncthreads();

    // ---------------- phase 1: geometry (2 pairs per thread) ----------------
    {
        float R0[12], R1[12];
#pragma unroll
        for (int k = 0; k < 12; ++k) {
            R0[k] = rt[(0 * NB + b) * 12 + k];
            R1[k] = rt[(1 * NB + b) * 12 + k];
        }
        const float CXY = 64.0f / 63.5f;

#pragma unroll
        for (int pp = 0; pp < 2; ++pp) {
            int pr   = tid + pp * 256;      // 0..511
            int nsub = pr >> 5;             // 0..15
            int pix  = pr & 31;             // 0..31
            int gp   = blockIdx.x * 32 + pix;
            float fx = (float)(gp & (NW - 1));
            float fy = (float)(gp >> 7);
            float d  = d_lds[pix] * s_lds[nsub];

#pragma unroll
            for (int vi = 0; vi < 2; ++vi) {
                const float* R = vi ? R1 : R0;
                float px = (R[0] * fx + R[1] * fy + R[2]) * d + R[9];
                float py = (R[3] * fx + R[4] * fy + R[5]) * d + R[10];
                float pz = (R[6] * fx + R[7] * fy + R[8]) * d + R[11];
                float invz = __builtin_amdgcn_rcpf(pz);
                float ix = (px * invz) * CXY - 0.5f;
                float iy = (py * invz) * CXY - 0.5f;

                float x0f = floorf(ix), y0f = floorf(iy);
                float wx1 = ix - x0f, wx0 = 1.f - wx1;
                float wy1 = iy - y0f, wy0 = 1.f - wy1;

                float mx0 = (x0f >= 0.f  && x0f <= 127.f) ? wx0 : 0.f;
                float mx1 = (x0f >= -1.f && x0f <= 126.f) ? wx1 : 0.f;
                float my0 = (y0f >= 0.f  && y0f <= 127.f) ? wy0 : 0.f;
                float my1 = (y0f >= -1.f && y0f <= 126.f) ? wy1 : 0.f;

                int xi0 = (int)fminf(fmaxf(x0f, 0.f), 127.f);
                int yi0 = (int)fminf(fmaxf(y0f, 0.f), 127.f);
                int xo  = (x0f >= 0.f && x0f <= 126.f) ? 8 : 0;
                int yo  = (y0f >= 0.f && y0f <= 126.f) ? NW * 8 : 0;

                GeomRec g;
                g.base = (yi0 * NW + xi0) * 8;
                g.xoyo = xo | (yo << 16);
                g.w01  = __builtin_bit_cast(unsigned int, pack2(-(mx0 * my0), -(mx1 * my0)));
                g.w23  = __builtin_bit_cast(unsigned int, pack2(-(mx0 * my1), -(mx1 * my1)));
                geom[vi][nsub][pix] = g;
            }
        }
    }
    __syncthreads();

    // ---------------- phase 2: pipelined taps + combine ---------------------
    const int grp = lane >> 3;       // pixel group in wave (0..7)
    const int gl  = lane & 7;        // uint4 slot in the 128B record
    const int pix2 = wv * 8 + grp;   // block-local pixel (0..31)

    const uint4* f0q = (const uint4*)(ftb) +
        ((size_t)(0 * NB + b) * NH * NW + blockIdx.x * 32 + pix2) * 8 + gl;
    const uint4* v1q = (const uint4*)(ftb) + ((size_t)(1 * NB + b) * NH * NW) * 8 + gl;
    const uint4* v2q = (const uint4*)(ftb) + ((size_t)(2 * NB + b) * NH * NW) * 8 + gl;

    const uint4 f0u = *f0q;

    // prologue: taps for i = 0 into the A set
    G4 gA0 = expand(geom[0][0][pix2]);
    G4 gA1 = expand(geom[1][0][pix2]);
    uint4 A00 = v1q[gA0.t0], A01 = v1q[gA0.t1], A02 = v1q[gA0.t2], A03 = v1q[gA0.t3];
    uint4 A10 = v2q[gA1.t0], A11 = v2q[gA1.t1], A12 = v2q[gA1.t2], A13 = v2q[gA1.t3];

    for (int it = 0; it < NSB / 2; ++it) {
        const int i0 = 2 * it, i1 = i0 + 1;

        // issue odd-index taps into the B set
        G4 gB0 = expand(geom[0][i1][pix2]);
        G4 gB1 = expand(geom[1][i1][pix2]);
        uint4 B00 = v1q[gB0.t0], B01 = v1q[gB0.t1], B02 = v1q[gB0.t2], B03 = v1q[gB0.t3];
        uint4 B10 = v2q[gB1.t0], B11 = v2q[gB1.t1], B12 = v2q[gB1.t2], B13 = v2q[gB1.t3];

        // combine even (B loads in flight -> vmcnt(8) wait, not a drain)
        float sv0 = combine(f0u, gA0, gA1, A00, A01, A02, A03, A10, A11, A12, A13);
        if (lane == 63) red[wv][i0] = sv0;

        // issue next even-index taps into the A set (clamped; no branch)
        const int i2 = (i0 + 2 < NSB) ? i0 + 2 : i0;
        gA0 = expand(geom[0][i2][pix2]);
        gA1 = expand(geom[1][i2][pix2]);
        A00 = v1q[gA0.t0]; A01 = v1q[gA0.t1]; A02 = v1q[gA0.t2]; A03 = v1q[gA0.t3];
        A10 = v2q[gA1.t0]; A11 = v2q[gA1.t1]; A12 = v2q[gA1.t2]; A13 = v2q[gA1.t3];

        // combine odd (A loads in flight)
        float sv1 = combine(f0u, gB0, gB1, B00, B01, B02, B03, B10, B11, B12, B13);
        if (lane == 63) red[wv][i1] = sv1;
    }

    __syncthreads();
    if (tid < NSB) {
        float t = red[0][tid] + red[1][tid] + red[2][tid] + red[3][tid];
        atomicAdd(&cost[b * NSC + nsg * NSB + tid], t * (0.5f / (float)(NH * NW)));
        __threadfence();
    }
    __syncthreads();

    // ---- completion counter; last block runs the finalize ----
    __shared__ unsigned int lastflag;
    if (tid == 0) {
        unsigned int prev = atomicAdd(counter, 1u);
        lastflag = (prev == (unsigned int)(total_blocks - 1)) ? 1u : 0u;
    }
    __syncthreads();
    if (lastflag && tid < NB * NSC) {
        __threadfence();
        int bb = tid >> 5;
        int ns = tid & 31;
        float c  = atomicAdd(&cost[bb * NSC + ns], 0.0f);  // coherent read
        float sv = scale[bb * NSC + ns];

        float m = c;
#pragma unroll
        for (int mk = 1; mk < 32; mk <<= 1) m = fmaxf(m, __shfl_xor(m, mk, 64));
        float e = __expf(c - m);
        float sum = e;
#pragma unroll
        for (int mk = 1; mk < 32; mk <<= 1) sum += __shfl_xor(sum, mk, 64);
        float val = (e / sum) * sv;
#pragma unroll
        for (int mk = 1; mk < 32; mk <<= 1) val += __shfl_xor(val, mk, 64);
        if (ns == 0) outp[bb] = val;
    }
}

// ---------------------------------------------------------------------------
extern "C" void kernel_launch(void* const* d_in, const int* in_sizes, int n_in,
                              void* d_out, int out_size, void* d_ws, size_t ws_size,
                              hipStream_t stream) {
    const float* features   = (const float*)d_in[0];  // (V,B,C,H,W)
    const float* intrinsics = (const float*)d_in[1];  // (V,B,3,3)
    const float* cam2world  = (const float*)d_in[2];  // (V,B,4,4)
    const float* scale_hypo = (const float*)d_in[3];  // (B,NS)
    const float* depth_init = (const float*)d_in[4];  // (B,H,W)
    float* out = (float*)d_out;                       // (B,)

    // workspace layout
    unsigned int* ftb = (unsigned int*)d_ws;                      // V*B*H*W*C/2 uints (f16 pairs)
    float* rt   = (float*)(ftb + (size_t)NV * NB * NH * NW * (NC / 2));
    float* cost = rt + 2 * NB * 12;                               // B*NS floats
    unsigned int* counter = (unsigned int*)(cost + NB * NSC);

    dim3 tgrid(NH, NV * NB);
    transpose_kernel<<<tgrid, 256, 0, stream>>>(features, ftb, intrinsics, cam2world,
                                                rt, cost, counter);

    dim3 cgrid(NH * NW / 32, NSC / NSB, NB);
    int total_blocks = cgrid.x * cgrid.y * cgrid.z;
    cost_kernel<<<cgrid, 256, 0, stream>>>(ftb, depth_init, scale_hypo, rt,
                                           cost, counter, out, total_blocks);
}

// Round 11
// 153.589 us; speedup vs baseline: 1.0263x; 1.0263x over previous
//
#include <hip/hip_runtime.h>
#include <math.h>

// Problem constants (from reference): V=3, B=2, C=64, NS=32, H=128, W=128
constexpr int NV = 3;
constexpr int NB = 2;
constexpr int NC = 64;
constexpr int NSC = 32;
constexpr int NH = 128;
constexpr int NW = 128;
constexpr int NSB = 16;  // ns values per block-pass (ns-inner for epipolar locality)

typedef _Float16 h2_t __attribute__((ext_vector_type(2)));

// ---------------------------------------------------------------------------
// DPP helpers (VALU cross-lane, no DS pipe).
// ---------------------------------------------------------------------------
template <int CTRL>
__device__ __forceinline__ float dpp_add(float x) {
    int s = __builtin_amdgcn_update_dpp(0, __float_as_int(x), CTRL, 0xf, 0xf, true);
    return x + __int_as_float(s);
}

__device__ __forceinline__ float dot2acc(h2_t a, float acc) {
#if __has_builtin(__builtin_amdgcn_fdot2)
    return __builtin_amdgcn_fdot2(a, a, acc, false);
#else
    float x = (float)a.x, y = (float)a.y;
    return acc + x * x + y * y;
#endif
}

__device__ __forceinline__ h2_t pack2(float a, float b) {
#if __has_builtin(__builtin_amdgcn_cvt_pkrtz)
    return __builtin_bit_cast(h2_t, __builtin_amdgcn_cvt_pkrtz(a, b));
#else
    h2_t r = { (_Float16)a, (_Float16)b };
    return r;
#endif
}

__device__ __forceinline__ unsigned int gc(const uint4& v, int j) {
    return j == 0 ? v.x : j == 1 ? v.y : j == 2 ? v.z : v.w;
}

// ---------------------------------------------------------------------------
// 4x4 inverse (adjugate, double precision) — mirrors jnp.linalg.inv fidelity
// ---------------------------------------------------------------------------
__device__ void inv4x4(const double* m, double* out) {
    double inv[16];
    inv[0]  =  m[5]*m[10]*m[15] - m[5]*m[11]*m[14] - m[9]*m[6]*m[15] + m[9]*m[7]*m[14] + m[13]*m[6]*m[11] - m[13]*m[7]*m[10];
    inv[4]  = -m[4]*m[10]*m[15] + m[4]*m[11]*m[14] + m[8]*m[6]*m[15] - m[8]*m[7]*m[14] - m[12]*m[6]*m[11] + m[12]*m[7]*m[10];
    inv[8]  =  m[4]*m[9]*m[15]  - m[4]*m[11]*m[13] - m[8]*m[5]*m[15] + m[8]*m[7]*m[13] + m[12]*m[5]*m[11] - m[12]*m[7]*m[9];
    inv[12] = -m[4]*m[9]*m[14]  + m[4]*m[10]*m[13] + m[8]*m[5]*m[14] - m[8]*m[6]*m[13] - m[12]*m[5]*m[10] + m[12]*m[6]*m[9];
    inv[1]  = -m[1]*m[10]*m[15] + m[1]*m[11]*m[14] + m[9]*m[2]*m[15] - m[9]*m[3]*m[14] - m[13]*m[2]*m[11] + m[13]*m[3]*m[10];
    inv[5]  =  m[0]*m[10]*m[15] - m[0]*m[11]*m[14] - m[8]*m[2]*m[15] + m[8]*m[3]*m[14] + m[12]*m[2]*m[11] - m[12]*m[3]*m[10];
    inv[9]  = -m[0]*m[9]*m[15]  + m[0]*m[11]*m[13] + m[8]*m[1]*m[15] - m[8]*m[3]*m[13] - m[12]*m[1]*m[11] + m[12]*m[3]*m[9];
    inv[13] =  m[0]*m[9]*m[14]  - m[0]*m[10]*m[13] - m[8]*m[1]*m[14] + m[8]*m[2]*m[13] + m[12]*m[1]*m[10] - m[12]*m[2]*m[9];
    inv[2]  =  m[1]*m[6]*m[15]  - m[1]*m[7]*m[14]  - m[5]*m[2]*m[15] + m[5]*m[3]*m[14] + m[13]*m[2]*m[7]  - m[13]*m[3]*m[6];
    inv[6]  = -m[0]*m[6]*m[15]  + m[0]*m[7]*m[14]  + m[4]*m[2]*m[15] - m[4]*m[3]*m[14] - m[12]*m[2]*m[7]  + m[12]*m[3]*m[6];
    inv[10] =  m[0]*m[5]*m[15]  - m[0]*m[7]*m[13]  - m[4]*m[1]*m[15] + m[4]*m[3]*m[13] + m[12]*m[1]*m[7]  - m[12]*m[3]*m[5];
    inv[14] = -m[0]*m[5]*m[14]  + m[0]*m[6]*m[13]  + m[4]*m[1]*m[14] - m[4]*m[2]*m[13] - m[12]*m[1]*m[6]  + m[12]*m[2]*m[5];
    inv[3]  = -m[1]*m[6]*m[11]  + m[1]*m[7]*m[10]  + m[5]*m[2]*m[11] - m[5]*m[3]*m[10] - m[9]*m[2]*m[7]   + m[9]*m[3]*m[6];
    inv[7]  =  m[0]*m[6]*m[11]  - m[0]*m[7]*m[10]  - m[4]*m[2]*m[11] + m[4]*m[3]*m[10] + m[8]*m[2]*m[7]   - m[8]*m[3]*m[6];
    inv[11] = -m[0]*m[5]*m[11]  + m[0]*m[7]*m[9]   + m[4]*m[1]*m[11] - m[4]*m[3]*m[9]  - m[8]*m[1]*m[7]   + m[8]*m[3]*m[5];
    inv[15] =  m[0]*m[5]*m[10]  - m[0]*m[6]*m[9]   - m[4]*m[1]*m[10] + m[4]*m[2]*m[9]  + m[8]*m[1]*m[6]   - m[8]*m[2]*m[5];
    double det = m[0]*inv[0] + m[1]*inv[4] + m[2]*inv[8] + m[3]*inv[12];
    det = 1.0 / det;
    for (int i = 0; i < 16; ++i) out[i] = inv[i] * det;
}

__device__ void mat4mul(const double* a, const double* b, double* o) {
    for (int i = 0; i < 4; ++i)
        for (int j = 0; j < 4; ++j) {
            double s = 0.0;
            for (int k = 0; k < 4; ++k) s += a[i*4+k] * b[k*4+j];
            o[i*4+j] = s;
        }
}

// ---------------------------------------------------------------------------
// Transpose + f16 compress: (V*B, C, H, W) fp32 -> (V*B, H*W, C) f16.
// One block per (vb, y) row. Block (0,0) additionally computes the homography
// rot/trans (threads 0..3), zeroes cost (4..67) and the counter (68).
// ---------------------------------------------------------------------------
__global__ __launch_bounds__(256) void transpose_kernel(const float* __restrict__ in,
                                                        unsigned int* __restrict__ out,
                                                        const float* __restrict__ intr,
                                                        const float* __restrict__ c2w,
                                                        float* __restrict__ rt,
                                                        float* __restrict__ cost,
                                                        unsigned int* __restrict__ counter) {
    __shared__ float tile[NC][NW + 1];
    const int y  = blockIdx.x;
    const int vb = blockIdx.y;

    for (int i = threadIdx.x; i < NC * NW; i += 256) {
        int c = i >> 7;
        int x = i & (NW - 1);
        tile[c][x] = in[((size_t)(vb * NC + c) * NH + y) * NW + x];
    }
    __syncthreads();
    // dst: per pixel a record of 64 f16 = 32 uints
    unsigned int* dst = out + ((size_t)vb * NH + y) * NW * (NC / 2);
    for (int i = threadIdx.x; i < NW * (NC / 2); i += 256) {
        int x  = i >> 5;         // /32
        int cp = i & 31;         // channel pair
        h2_t h = { (_Float16)tile[2 * cp][x], (_Float16)tile[2 * cp + 1][x] };
        dst[x * (NC / 2) + cp] = __builtin_bit_cast(unsigned int, h);
    }

    // ---- fused setup (one block only) ----
    if (blockIdx.x == 0 && blockIdx.y == 0) {
        int t = threadIdx.x;
        if (t >= 4 && t < 4 + NB * NSC) cost[t - 4] = 0.f;
        if (t == 4 + NB * NSC) *counter = 0u;
        if (t < 2 * NB) {
            int vi = t >> 1;
            int b  = t & 1;
            int v  = vi + 1;

            double src_c2w[16], ref_c2w[16];
            for (int i = 0; i < 16; ++i) {
                src_c2w[i] = (double)c2w[(v * NB + b) * 16 + i];
                ref_c2w[i] = (double)c2w[(0 * NB + b) * 16 + i];
            }
            double src_w2c[16], ref_w2c[16];
            inv4x4(src_c2w, src_w2c);
            inv4x4(ref_c2w, ref_w2c);

            double srcP[16], refP[16];
            for (int i = 0; i < 16; ++i) { srcP[i] = src_w2c[i]; refP[i] = ref_w2c[i]; }
            for (int r = 0; r < 3; ++r)
                for (int c = 0; c < 3; ++c) {
                    srcP[r*4+c] = (double)intr[(v * NB + b) * 9 + r*3 + c];
                    refP[r*4+c] = (double)intr[(0 * NB + b) * 9 + r*3 + c];
                }

            double M1[16], M2[16], M2inv[16];
            mat4mul(srcP, src_w2c, M1);
            mat4mul(refP, ref_w2c, M2);
            inv4x4(M2, M2inv);
            double proj[16];
            mat4mul(M1, M2inv, proj);

            float* o = rt + (vi * NB + b) * 12;
            o[0] = (float)proj[0];  o[1] = (float)proj[1];  o[2]  = (float)proj[2];
            o[3] = (float)proj[4];  o[4] = (float)proj[5];  o[5]  = (float)proj[6];
            o[6] = (float)proj[8];  o[7] = (float)proj[9];  o[8]  = (float)proj[10];
            o[9] = (float)proj[3];  o[10] = (float)proj[7]; o[11] = (float)proj[11];
        }
    }
}

// ---------------------------------------------------------------------------
// Geometry record: tap base index (uint4 units), packed neighbor offsets,
// 4 bilinear weights (f16, pre-negated). 16 B -> one ds op.
// ---------------------------------------------------------------------------
struct alignas(16) GeomRec {
    int base;
    int xoyo;          // xo | (yo<<16), in uint4 units
    unsigned int w01;  // h2 {-w00, -w01}
    unsigned int w23;  // h2 {-w10, -w11}
};

struct G4 {            // expanded form
    int t0, t1, t2, t3;
    h2_t w0s, w1s, w2s, w3s;  // splatted negated weights
};

__device__ __forceinline__ G4 expand(GeomRec g) {
    G4 o;
    int xo = g.xoyo & 0xffff;
    int yo = g.xoyo >> 16;
    o.t0 = g.base;
    o.t1 = g.base + xo;
    o.t2 = g.base + yo;
    o.t3 = g.base + yo + xo;
    h2_t w01 = __builtin_bit_cast(h2_t, g.w01);
    h2_t w23 = __builtin_bit_cast(h2_t, g.w23);
    o.w0s = h2_t{w01.x, w01.x};
    o.w1s = h2_t{w01.y, w01.y};
    o.w2s = h2_t{w23.x, w23.x};
    o.w3s = h2_t{w23.y, w23.y};
    return o;
}

// Bilinear combine for both views + DPP reduce -> wave total (valid lane 63).
__device__ __forceinline__ float combine(const uint4& f0u, const G4& g0, const G4& g1,
                                         const uint4& a0, const uint4& a1,
                                         const uint4& a2, const uint4& a3,
                                         const uint4& b0, const uint4& b1,
                                         const uint4& b2, const uint4& b3) {
    float sq1 = 0.f, sq2 = 0.f;
    h2_t r[4];
#pragma unroll
    for (int j = 0; j < 4; ++j) {
        h2_t rr = __builtin_bit_cast(h2_t, gc(f0u, j));
        rr += __builtin_bit_cast(h2_t, gc(a0, j)) * g0.w0s;
        rr += __builtin_bit_cast(h2_t, gc(a1, j)) * g0.w1s;
        rr += __builtin_bit_cast(h2_t, gc(a2, j)) * g0.w2s;
        rr += __builtin_bit_cast(h2_t, gc(a3, j)) * g0.w3s;
        r[j] = rr;
        sq1 = dot2acc(rr, sq1);
    }
#pragma unroll
    for (int j = 0; j < 4; ++j) {
        h2_t rr = r[j];
        rr += __builtin_bit_cast(h2_t, gc(b0, j)) * g1.w0s;
        rr += __builtin_bit_cast(h2_t, gc(b1, j)) * g1.w1s;
        rr += __builtin_bit_cast(h2_t, gc(b2, j)) * g1.w2s;
        rr += __builtin_bit_cast(h2_t, gc(b3, j)) * g1.w3s;
        sq2 = dot2acc(rr, sq2);
    }
    // 8-lane group reduce (row_shr prefix; tails at lanes 7,15,...)
    sq1 = dpp_add<0x111>(sq1);
    sq1 = dpp_add<0x112>(sq1);
    sq1 = dpp_add<0x114>(sq1);
    sq2 = dpp_add<0x111>(sq2);
    sq2 = dpp_add<0x112>(sq2);
    sq2 = dpp_add<0x114>(sq2);
    float sv = sqrtf(sq1) + sqrtf(sq2);
    sv = dpp_add<0x118>(sv);   // row_shr:8
    sv = dpp_add<0x142>(sv);   // row_bcast:15
    sv = dpp_add<0x143>(sv);   // row_bcast:31 -> wave total in lane 63
    return sv;
}

// ---------------------------------------------------------------------------
// Main cost kernel v10.
// Phase 1: lane-parallel geometry -> GeomRec in LDS (as v8).
// Phase 2: double-buffered pipeline with sched_barrier(0) fences pinning
//          program order:  issue B(i+1) | SB | combine A(i) | issue A(i+2)
//          | SB | combine B(i+1).  The fences stop the pre-RA scheduler from
//          sinking the prefetch loads to their uses (the failure mode of v8/
//          v9, visible as VGPR=36..40).  With order pinned, the compiler's
//          automatic waitcnt insertion yields counted vmcnt waits (8 loads
//          always outstanding).
// Grid: (H*W/32, NS/NSB, B), block 256.
// ---------------------------------------------------------------------------
__global__ __launch_bounds__(256) void cost_kernel(
    const unsigned int* __restrict__ ftb, // (V, B, H*W, C) f16 features
    const float* __restrict__ depth,      // (B, H, W)
    const float* __restrict__ scale,      // (B, NS)
    const float* __restrict__ rt,         // (2, B, 12)
    float* __restrict__ cost,             // (B, NS) -- zeroed by transpose
    unsigned int* __restrict__ counter,   // completion counter -- zeroed
    float* __restrict__ outp,             // (B,) final output
    int total_blocks)
{
    const int tid  = threadIdx.x;
    const int lane = tid & 63;
    const int wv   = tid >> 6;
    const int nsg  = blockIdx.y;
    const int b    = blockIdx.z;

    __shared__ float s_lds[NSB];
    __shared__ float d_lds[32];
    __shared__ GeomRec geom[2][NSB][32];
    __shared__ float red[4][NSB];

    if (tid < NSB) s_lds[tid] = scale[b * NSC + nsg * NSB + tid];
    if (tid < 32)  d_lds[tid] = depth[b * NH * NW + blockIdx.x * 32 + tid];
    __syncthreads();

    // ---------------- phase 1: geometry (2 pairs per thread) ----------------
    {
        float R0[12], R1[12];
#pragma unroll
        for (int k = 0; k < 12; ++k) {
            R0[k] = rt[(0 * NB + b) * 12 + k];
            R1[k] = rt[(1 * NB + b) * 12 + k];
        }
        const float CXY = 64.0f / 63.5f;

#pragma unroll
        for (int pp = 0; pp < 2; ++pp) {
            int pr   = tid + pp * 256;      // 0..511
            int nsub = pr >> 5;             // 0..15
            int pix  = pr & 31;             // 0..31
            int gp   = blockIdx.x * 32 + pix;
            float fx = (float)(gp & (NW - 1));
            float fy = (float)(gp >> 7);
            float d  = d_lds[pix] * s_lds[nsub];

#pragma unroll
            for (int vi = 0; vi < 2; ++vi) {
                const float* R = vi ? R1 : R0;
                float px = (R[0] * fx + R[1] * fy + R[2]) * d + R[9];
                float py = (R[3] * fx + R[4] * fy + R[5]) * d + R[10];
                float pz = (R[6] * fx + R[7] * fy + R[8]) * d + R[11];
                float invz = __builtin_amdgcn_rcpf(pz);
                float ix = (px * invz) * CXY - 0.5f;
                float iy = (py * invz) * CXY - 0.5f;

                float x0f = floorf(ix), y0f = floorf(iy);
                float wx1 = ix - x0f, wx0 = 1.f - wx1;
                float wy1 = iy - y0f, wy0 = 1.f - wy1;

                float mx0 = (x0f >= 0.f  && x0f <= 127.f) ? wx0 : 0.f;
                float mx1 = (x0f >= -1.f && x0f <= 126.f) ? wx1 : 0.f;
                float my0 = (y0f >= 0.f  && y0f <= 127.f) ? wy0 : 0.f;
                float my1 = (y0f >= -1.f && y0f <= 126.f) ? wy1 : 0.f;

                int xi0 = (int)fminf(fmaxf(x0f, 0.f), 127.f);
                int yi0 = (int)fminf(fmaxf(y0f, 0.f), 127.f);
                int xo  = (x0f >= 0.f && x0f <= 126.f) ? 8 : 0;
                int yo  = (y0f >= 0.f && y0f <= 126.f) ? NW * 8 : 0;

                GeomRec g;
                g.base = (yi0 * NW + xi0) * 8;
                g.xoyo = xo | (yo << 16);
                g.w01  = __builtin_bit_cast(unsigned int, pack2(-(mx0 * my0), -(mx1 * my0)));
                g.w23  = __builtin_bit_cast(unsigned int, pack2(-(mx0 * my1), -(mx1 * my1)));
                geom[vi][nsub][pix] = g;
            }
        }
    }
    __syncthreads();

    // ---------------- phase 2: pipelined taps + combine ---------------------
    const int grp = lane >> 3;       // pixel group in wave (0..7)
    const int gl  = lane & 7;        // uint4 slot in the 128B record
    const int pix2 = wv * 8 + grp;   // block-local pixel (0..31)

    const uint4* f0q = (const uint4*)(ftb) +
        ((size_t)(0 * NB + b) * NH * NW + blockIdx.x * 32 + pix2) * 8 + gl;
    const uint4* v1q = (const uint4*)(ftb) + ((size_t)(1 * NB + b) * NH * NW) * 8 + gl;
    const uint4* v2q = (const uint4*)(ftb) + ((size_t)(2 * NB + b) * NH * NW) * 8 + gl;

    const uint4 f0u = *f0q;

    // prologue: taps for i = 0 into the A set
    G4 gA0 = expand(geom[0][0][pix2]);
    G4 gA1 = expand(geom[1][0][pix2]);
    uint4 A00 = v1q[gA0.t0], A01 = v1q[gA0.t1], A02 = v1q[gA0.t2], A03 = v1q[gA0.t3];
    uint4 A10 = v2q[gA1.t0], A11 = v2q[gA1.t1], A12 = v2q[gA1.t2], A13 = v2q[gA1.t3];

    for (int it = 0; it < NSB / 2; ++it) {
        const int i0 = 2 * it, i1 = i0 + 1;

        // issue odd-index taps into the B set
        G4 gB0 = expand(geom[0][i1][pix2]);
        G4 gB1 = expand(geom[1][i1][pix2]);
        uint4 B00 = v1q[gB0.t0], B01 = v1q[gB0.t1], B02 = v1q[gB0.t2], B03 = v1q[gB0.t3];
        uint4 B10 = v2q[gB1.t0], B11 = v2q[gB1.t1], B12 = v2q[gB1.t2], B13 = v2q[gB1.t3];

        // pin: B loads stay issued above the A combine
        __builtin_amdgcn_sched_barrier(0);

        // combine even (B loads in flight -> counted vmcnt wait, not a drain)
        float sv0 = combine(f0u, gA0, gA1, A00, A01, A02, A03, A10, A11, A12, A13);
        if (lane == 63) red[wv][i0] = sv0;

        // issue next even-index taps into the A set (clamped; no branch)
        const int i2 = (i0 + 2 < NSB) ? i0 + 2 : i0;
        gA0 = expand(geom[0][i2][pix2]);
        gA1 = expand(geom[1][i2][pix2]);
        A00 = v1q[gA0.t0]; A01 = v1q[gA0.t1]; A02 = v1q[gA0.t2]; A03 = v1q[gA0.t3];
        A10 = v2q[gA1.t0]; A11 = v2q[gA1.t1]; A12 = v2q[gA1.t2]; A13 = v2q[gA1.t3];

        // pin: A loads stay issued above the B combine
        __builtin_amdgcn_sched_barrier(0);

        // combine odd (A loads in flight)
        float sv1 = combine(f0u, gB0, gB1, B00, B01, B02, B03, B10, B11, B12, B13);
        if (lane == 63) red[wv][i1] = sv1;
    }

    __syncthreads();
    if (tid < NSB) {
        float t = red[0][tid] + red[1][tid] + red[2][tid] + red[3][tid];
        atomicAdd(&cost[b * NSC + nsg * NSB + tid], t * (0.5f / (float)(NH * NW)));
        __threadfence();
    }
    __syncthreads();

    // ---- completion counter; last block runs the finalize ----
    __shared__ unsigned int lastflag;
    if (tid == 0) {
        unsigned int prev = atomicAdd(counter, 1u);
        lastflag = (prev == (unsigned int)(total_blocks - 1)) ? 1u : 0u;
    }
    __syncthreads();
    if (lastflag && tid < NB * NSC) {
        __threadfence();
        int bb = tid >> 5;
        int ns = tid & 31;
        float c  = atomicAdd(&cost[bb * NSC + ns], 0.0f);  // coherent read
        float sv = scale[bb * NSC + ns];

        float m = c;
#pragma unroll
        for (int mk = 1; mk < 32; mk <<= 1) m = fmaxf(m, __shfl_xor(m, mk, 64));
        float e = __expf(c - m);
        float sum = e;
#pragma unroll
        for (int mk = 1; mk < 32; mk <<= 1) sum += __shfl_xor(sum, mk, 64);
        float val = (e / sum) * sv;
#pragma unroll
        for (int mk = 1; mk < 32; mk <<= 1) val += __shfl_xor(val, mk, 64);
        if (ns == 0) outp[bb] = val;
    }
}

// ---------------------------------------------------------------------------
extern "C" void kernel_launch(void* const* d_in, const int* in_sizes, int n_in,
                              void* d_out, int out_size, void* d_ws, size_t ws_size,
                              hipStream_t stream) {
    const float* features   = (const float*)d_in[0];  // (V,B,C,H,W)
    const float* intrinsics = (const float*)d_in[1];  // (V,B,3,3)
    const float* cam2world  = (const float*)d_in[2];  // (V,B,4,4)
    const float* scale_hypo = (const float*)d_in[3];  // (B,NS)
    const float* depth_init = (const float*)d_in[4];  // (B,H,W)
    float* out = (float*)d_out;                       // (B,)

    // workspace layout
    unsigned int* ftb = (unsigned int*)d_ws;                      // V*B*H*W*C/2 uints (f16 pairs)
    float* rt   = (float*)(ftb + (size_t)NV * NB * NH * NW * (NC / 2));
    float* cost = rt + 2 * NB * 12;                               // B*NS floats
    unsigned int* counter = (unsigned int*)(cost + NB * NSC);

    dim3 tgrid(NH, NV * NB);
    transpose_kernel<<<tgrid, 256, 0, stream>>>(features, ftb, intrinsics, cam2world,
                                                rt, cost, counter);

    dim3 cgrid(NH * NW / 32, NSC / NSB, NB);
    int total_blocks = cgrid.x * cgrid.y * cgrid.z;
    cost_kernel<<<cgrid, 256, 0, stream>>>(ftb, depth_init, scale_hypo, rt,
                                           cost, counter, out, total_blocks);
}